// Round 11
// baseline (4033.661 us; speedup 1.0000x reference)
//
#include <hip/hip_runtime.h>
#include <cmath>

#define D 64
#define NCHMAX 2048
#define PA_TILE 4096
#define SCHUNK 2048

__device__ __forceinline__ float wave_reduce_sum(float v) {
  #pragma unroll
  for (int off = 32; off > 0; off >>= 1) v += __shfl_xor(v, off, 64);
  return v;
}
__device__ __forceinline__ float wave_reduce_max(float v) {
  #pragma unroll
  for (int off = 32; off > 0; off >>= 1) v = fmaxf(v, __shfl_xor(v, off, 64));
  return v;
}
__device__ __forceinline__ int wave_reduce_sum_i(int v) {
  #pragma unroll
  for (int off = 32; off > 0; off >>= 1) v += __shfl_xor(v, off, 64);
  return v;
}

// ---- row accumulate over mini-CSR: 4 edge-groups x 16 lanes, float4 ----
__device__ __forceinline__ void row_accum4(const int2* __restrict__ edata, int lo, int hi,
                                           const float* __restrict__ ftab, int g, int c4,
                                           float4& acc) {
  for (int base = lo; base < hi; base += 8) {
    int j0 = base + g, j1 = base + 4 + g;
    int2 e0 = (j0 < hi) ? edata[j0] : make_int2(0, 0);
    int2 e1 = (j1 < hi) ? edata[j1] : make_int2(0, 0);
    float4 f0 = *(const float4*)(ftab + (size_t)e0.x * D + c4);
    float4 f1 = *(const float4*)(ftab + (size_t)e1.x * D + c4);
    float v0 = __int_as_float(e0.y), v1 = __int_as_float(e1.y);
    acc.x = fmaf(v0, f0.x, acc.x); acc.y = fmaf(v0, f0.y, acc.y);
    acc.z = fmaf(v0, f0.z, acc.z); acc.w = fmaf(v0, f0.w, acc.w);
    acc.x = fmaf(v1, f1.x, acc.x); acc.y = fmaf(v1, f1.y, acc.y);
    acc.z = fmaf(v1, f1.z, acc.z); acc.w = fmaf(v1, f1.w, acc.w);
  }
}
__device__ __forceinline__ float4 cg_reduce4(float4 a) {
  a.x += __shfl_xor(a.x, 16, 64); a.x += __shfl_xor(a.x, 32, 64);
  a.y += __shfl_xor(a.y, 16, 64); a.y += __shfl_xor(a.y, 32, 64);
  a.z += __shfl_xor(a.z, 16, 64); a.z += __shfl_xor(a.z, 32, 64);
  a.w += __shfl_xor(a.w, 16, 64); a.w += __shfl_xor(a.w, 32, 64);
  return a;
}

// ---------------- setup ----------------

__global__ void mark_usel(const int* __restrict__ uid, int* __restrict__ usel, int B) {
  int b = blockIdx.x * blockDim.x + threadIdx.x;
  if (b < B) usel[uid[b]] = 1;
}

// ---- chunk histogram (LDS-aggregated) + mini-degree count ----
__global__ __launch_bounds__(256) void hist_both(
    const int* __restrict__ src, int n2, int h, int NU,
    int nchU, int shiftI, int nch,
    const int* __restrict__ usel, int* __restrict__ minideg, int* __restrict__ ghist) {
  __shared__ int lh[NCHMAX];
  int t = threadIdx.x;
  for (int i = t; i < nch; i += 256) lh[i] = 0;
  __syncthreads();
  int base = blockIdx.x * PA_TILE;
  #pragma unroll
  for (int k = 0; k < 16; ++k) {
    int e = base + k * 256 + t;
    if (e >= n2) break;
    int s = src[e];
    if (e < h) {
      if (nchU > 0) atomicAdd(&lh[s >> 7], 1);
      if (usel[s]) atomicAdd(&minideg[s], 1);
    } else {
      atomicAdd(&lh[nchU + ((s - NU) >> shiftI)], 1);
    }
  }
  __syncthreads();
  int sh = (blockIdx.x & 7) * nch;
  for (int i = t; i < nch; i += 256) {
    int c = lh[i];
    if (c) atomicAdd(&ghist[sh + i], c);
  }
}

// ---- tiny chunk scan: sum 8 shards, exclusive scan -> chunkptr, ccur ----
__global__ __launch_bounds__(256) void scan_chunks(const int* __restrict__ ghist, int nch,
                                                   int* __restrict__ chunkptr,
                                                   int* __restrict__ ccur) {
  __shared__ int part[256];
  int t = threadIdx.x;
  int seg = (nch + 255) / 256;
  int loc[8];
  int s = 0;
  for (int i = 0; i < seg; ++i) {
    int idx = t * seg + i;
    int c = 0;
    if (idx < nch)
      for (int sh = 0; sh < 8; ++sh) c += ghist[sh * nch + idx];
    loc[i] = c; s += c;
  }
  part[t] = s;
  __syncthreads();
  for (int off = 1; off < 256; off <<= 1) {
    int v = (t >= off) ? part[t - off] : 0;
    __syncthreads();
    part[t] += v;
    __syncthreads();
  }
  int run = t ? part[t - 1] : 0;
  for (int i = 0; i < seg; ++i) {
    int idx = t * seg + i;
    if (idx < nch) { chunkptr[idx] = run; ccur[idx] = run; run += loc[i]; }
  }
  if (t == 255) chunkptr[nch] = run;
}

// ---- big scan over minideg[NU] -> minirowptr, minicur ----
__global__ void scan_p1(const int* __restrict__ deg, int* __restrict__ bsum, int N) {
  int b = blockIdx.x, t = threadIdx.x;
  int lo = b * SCHUNK;
  int s = 0;
  #pragma unroll
  for (int k = 0; k < 8; ++k) { int i = lo + k * 256 + t; if (i < N) s += deg[i]; }
  s = wave_reduce_sum_i(s);
  __shared__ int ws[4];
  if ((t & 63) == 0) ws[t >> 6] = s;
  __syncthreads();
  if (t == 0) bsum[b] = ws[0] + ws[1] + ws[2] + ws[3];
}

__global__ __launch_bounds__(1024) void scan_p2(int* __restrict__ bsum, int nb,
                                                int* __restrict__ rowptr, int N) {
  __shared__ int arr[1024];
  int t = threadIdx.x;
  int v = (t < nb) ? bsum[t] : 0;
  arr[t] = v; __syncthreads();
  for (int off = 1; off < 1024; off <<= 1) {
    int x = (t >= off) ? arr[t - off] : 0;
    __syncthreads();
    arr[t] += x;
    __syncthreads();
  }
  if (t < nb) bsum[t] = t ? arr[t - 1] : 0;
  if (t == 0) rowptr[N] = arr[nb - 1];
}

__global__ void scan_p3(const int* __restrict__ deg, const int* __restrict__ bsum,
                        int* __restrict__ rowptr, int* __restrict__ cursor, int N) {
  int b = blockIdx.x, t = threadIdx.x;
  int lane = t & 63, wid = t >> 6;
  int base = b * SCHUNK + t * 8;
  int x[8], excl[8], s = 0;
  #pragma unroll
  for (int k = 0; k < 8; ++k) x[k] = (base + k < N) ? deg[base + k] : 0;
  #pragma unroll
  for (int k = 0; k < 8; ++k) { excl[k] = s; s += x[k]; }
  int incl = s;
  #pragma unroll
  for (int off = 1; off < 64; off <<= 1) {
    int y = __shfl_up(incl, off, 64);
    if (lane >= off) incl += y;
  }
  int wave_excl = incl - s;
  __shared__ int wsumS[4];
  if (lane == 63) wsumS[wid] = incl;
  __syncthreads();
  int wo = 0;
  for (int w = 0; w < wid; ++w) wo += wsumS[w];
  int off0 = bsum[b] + wo + wave_excl;
  #pragma unroll
  for (int k = 0; k < 8; ++k) {
    int i = base + k;
    if (i < N) { rowptr[i] = off0 + excl[k]; cursor[i] = off0 + excl[k]; }
  }
}

// ---- scatter by chunk: block-local counting sort, burst writes ----
// payload word0 = dstLocal | (srcLocal7 << 17); word1 = val bits
__global__ __launch_bounds__(256) void scatter_both(
    const int* __restrict__ src, const int* __restrict__ dst,
    const float* __restrict__ vals, int* __restrict__ ccur, int2* __restrict__ edata,
    int n2, int h, int NU, int nchU, int shiftI, int nch) {
  __shared__ int lh[NCHMAX];
  __shared__ int lbase[NCHMAX + 1];
  __shared__ int gofs[NCHMAX];
  __shared__ int lcur[NCHMAX];
  __shared__ int part[256];
  __shared__ uint2 sorted[PA_TILE];
  __shared__ unsigned short sbkt[PA_TILE];
  int t = threadIdx.x;
  for (int i = t; i < nch; i += 256) lh[i] = 0;
  __syncthreads();

  int base = blockIdx.x * PA_TILE;
  int mykey[16]; unsigned myrec[16], myval[16];
  #pragma unroll
  for (int k = 0; k < 16; ++k) {
    int e = base + k * 256 + t;
    int key = -1; unsigned rec = 0, vb = 0;
    if (e < n2) {
      int s = src[e];
      if (e < h) {
        if (nchU > 0) {
          key = s >> 7;
          rec = (unsigned)(dst[e] - NU) | ((unsigned)(s & 127) << 17);
        }
      } else {
        int il = s - NU;
        key = nchU + (il >> shiftI);
        rec = (unsigned)dst[e] | ((unsigned)(il & 127) << 17);
      }
      if (key >= 0) vb = __float_as_uint(vals[e]);
    }
    mykey[k] = key; myrec[k] = rec; myval[k] = vb;
    if (key >= 0) atomicAdd(&lh[key], 1);
  }
  __syncthreads();
  // parallel exclusive scan of lh -> lbase
  int seg = (nch + 255) / 256;
  int loc[8]; int ssum = 0;
  for (int i = 0; i < seg; ++i) {
    int idx = t * seg + i;
    loc[i] = (idx < nch) ? lh[idx] : 0; ssum += loc[i];
  }
  part[t] = ssum;
  __syncthreads();
  for (int off = 1; off < 256; off <<= 1) {
    int v = (t >= off) ? part[t - off] : 0;
    __syncthreads();
    part[t] += v;
    __syncthreads();
  }
  int run = t ? part[t - 1] : 0;
  for (int i = 0; i < seg; ++i) {
    int idx = t * seg + i;
    if (idx < nch) { lbase[idx] = run; run += loc[i]; }
  }
  if (t == 255) lbase[nch] = run;
  __syncthreads();
  for (int i = t; i < nch; i += 256) {
    int c = lh[i];
    if (c) gofs[i] = atomicAdd(&ccur[i], c) - lbase[i];
    lcur[i] = lbase[i];
  }
  __syncthreads();
  #pragma unroll
  for (int k = 0; k < 16; ++k) {
    int key = mykey[k];
    if (key >= 0) {
      int slot = atomicAdd(&lcur[key], 1);
      sorted[slot] = make_uint2(myrec[k], myval[k]);
      sbkt[slot] = (unsigned short)key;
    }
  }
  __syncthreads();
  int total = lbase[nch];
  for (int i = t; i < total; i += 256) {
    int k2 = sbkt[i];
    uint2 r = sorted[i];
    edata[(size_t)(gofs[k2] + i)] = make_int2((int)r.x, (int)r.y);
  }
}

// ---- mini-CSR scatter for selected user rows ----
__global__ void mini_scatter(const int* __restrict__ src, const int* __restrict__ dst,
                             const float* __restrict__ vals, const int* __restrict__ usel,
                             int* __restrict__ minicur, int2* __restrict__ edataM,
                             int h, int NU) {
  int e = blockIdx.x * blockDim.x + threadIdx.x;
  if (e >= h) return;
  int s = src[e];
  if (!usel[s]) return;
  int pos = atomicAdd(&minicur[s], 1);
  edataM[pos] = make_int2(dst[e] - NU, __float_as_int(vals[e]));
}

// ---- chunk SpMM, single table: out[row] = sum v * ftab[d] ----
__global__ __launch_bounds__(256) void spmm_chunk_s(
    const int* __restrict__ chunkptr, int coff, const int2* __restrict__ edata,
    const float* __restrict__ ftab, float* __restrict__ out, int rpc, int nrows) {
  __shared__ float acc[128 * D];
  int c = blockIdx.x, t = threadIdx.x;
  int wid = t >> 6, lane = t & 63;
  for (int i = t; i < rpc * D; i += 256) acc[i] = 0.f;
  __syncthreads();
  int lo = chunkptr[coff + c], hi = chunkptr[coff + c + 1];
  for (int j0 = lo + wid * 8; j0 < hi; j0 += 32) {
    #pragma unroll 8
    for (int u = 0; u < 8; ++u) {
      int j = j0 + u;
      if (j < hi) {
        int2 e = edata[j];
        int d = e.x & 0x1FFFF;
        int r = (e.x >> 17) & (rpc - 1);
        float v = __int_as_float(e.y);
        atomicAdd(&acc[r * D + lane], v * ftab[(size_t)d * D + lane]);
      }
    }
  }
  __syncthreads();
  int rowbase = c * rpc;
  for (int r = wid; r < rpc; r += 4) {
    int row = rowbase + r;
    if (row < nrows) out[(size_t)row * D + lane] = acc[r * D + lane];
  }
}

// ---- chunk SpMM, dual table + fused output:
// il1[row]=sum v*userF[d]; itemOut[row]=(itemF[row]+il1+sum v*ul1[d])/3
__global__ __launch_bounds__(256) void spmm_chunk_d(
    const int* __restrict__ chunkptr, int coff, const int2* __restrict__ edata,
    const float* __restrict__ userF, const float* __restrict__ ul1,
    const float* __restrict__ itemF, float* __restrict__ il1,
    float* __restrict__ itemOut, int rpc, int nrows) {
  __shared__ float a1[64 * D];
  __shared__ float a2[64 * D];
  int c = blockIdx.x, t = threadIdx.x;
  int wid = t >> 6, lane = t & 63;
  for (int i = t; i < rpc * D; i += 256) { a1[i] = 0.f; a2[i] = 0.f; }
  __syncthreads();
  int lo = chunkptr[coff + c], hi = chunkptr[coff + c + 1];
  for (int j0 = lo + wid * 8; j0 < hi; j0 += 32) {
    #pragma unroll 8
    for (int u = 0; u < 8; ++u) {
      int j = j0 + u;
      if (j < hi) {
        int2 e = edata[j];
        int d = e.x & 0x1FFFF;
        int r = (e.x >> 17) & (rpc - 1);
        float v = __int_as_float(e.y);
        size_t o = (size_t)d * D + lane;
        atomicAdd(&a1[r * D + lane], v * userF[o]);
        atomicAdd(&a2[r * D + lane], v * ul1[o]);
      }
    }
  }
  __syncthreads();
  int rowbase = c * rpc;
  for (int r = wid; r < rpc; r += 4) {
    int row = rowbase + r;
    if (row < nrows) {
      size_t o = (size_t)row * D + lane;
      float x1 = a1[r * D + lane];
      il1[o] = x1;
      itemOut[o] = (itemF[o] + x1 + a2[r * D + lane]) * (1.f / 3.f);
    }
  }
}

// ---- mini-CSR per-row kernels (selected users only) ----

// layer1 at batch user rows: ul1[uid[b]] = sum v*itemF[d]
__global__ void spmm_l1_uid(const int* __restrict__ rowptr, const int2* __restrict__ edata,
                            const float* __restrict__ itemF, float* __restrict__ ul1,
                            const int* __restrict__ uid, int B) {
  int b = blockIdx.x * 4 + (threadIdx.x >> 6);
  if (b >= B) return;
  int lane = threadIdx.x & 63, g = lane >> 4, c4 = (lane & 15) * 4;
  int r = uid[b];
  float4 a = make_float4(0.f, 0.f, 0.f, 0.f);
  row_accum4(edata, rowptr[r], rowptr[r + 1], itemF, g, c4, a);
  a = cg_reduce4(a);
  if (g == 0) *(float4*)(ul1 + (size_t)r * D + c4) = a;
}

// layer2+avg at batch users: ug[b] (+)= (userF[u] + ul1[u] + sum v*il1[d]) / 3
__global__ void final_uid(const int* __restrict__ rowptr, const int2* __restrict__ edata,
                          const float* __restrict__ il1, const float* __restrict__ ul1,
                          const float* __restrict__ userF, const int* __restrict__ uid,
                          float* __restrict__ ug, int add, int B) {
  int b = blockIdx.x * 4 + (threadIdx.x >> 6);
  if (b >= B) return;
  int lane = threadIdx.x & 63, g = lane >> 4, c4 = (lane & 15) * 4;
  int u = uid[b];
  float4 a = make_float4(0.f, 0.f, 0.f, 0.f);
  row_accum4(edata, rowptr[u], rowptr[u + 1], il1, g, c4, a);
  a = cg_reduce4(a);
  if (g == 0) {
    size_t uo = (size_t)u * D + c4;
    float4 uf = *(const float4*)(userF + uo);
    float4 ul = *(const float4*)(ul1 + uo);
    float4 res;
    res.x = (uf.x + ul.x + a.x) * (1.f / 3.f);
    res.y = (uf.y + ul.y + a.y) * (1.f / 3.f);
    res.z = (uf.z + ul.z + a.z) * (1.f / 3.f);
    res.w = (uf.w + ul.w + a.w) * (1.f / 3.f);
    float4* dstp = (float4*)(ug + (size_t)b * D + c4);
    if (add) {
      float4 old = *dstp;
      res.x += old.x; res.y += old.y; res.z += old.z; res.w += old.w;
    }
    *dstp = res;
  }
}

// ---------------- fused attention + MLP + output ----------------

__global__ __launch_bounds__(64) void attn_final(
    const float* __restrict__ e1, const float* __restrict__ pe,
    const int* __restrict__ seq, const int* __restrict__ mask,
    const float* __restrict__ wq_w, const float* __restrict__ wq_b,
    const float* __restrict__ wk_w, const float* __restrict__ wk_b,
    const float* __restrict__ wv_w, const float* __restrict__ wv_b,
    const float* __restrict__ mlp_w, const float* __restrict__ mlp_b,
    const float* __restrict__ ug, const float* __restrict__ c1,
    const int* __restrict__ cid, float* __restrict__ out, int T) {
  __shared__ float xs[64][D];
  __shared__ float wks[D * D];
  __shared__ float wvs[D * D];
  __shared__ float ps[D];
  __shared__ float ys[D];
  __shared__ float atts[D];
  int b = blockIdx.x, d = threadIdx.x;

  for (int i = d; i < D * D; i += 64) { wks[i] = wk_w[i]; wvs[i] = wv_w[i]; }
  for (int t = 0; t < T; ++t) {
    int sidx = seq[b * T + t];
    xs[t][d] = e1[(size_t)sidx * D + d] + pe[t * D + d];
  }
  __syncthreads();

  float qd = wq_b[d];
  #pragma unroll 4
  for (int j = 0; j < D; ++j) qd = fmaf(xs[T - 1][j], wq_w[j * D + d], qd);
  if (mask[b * T + (T - 1)] == 0) qd = -100000.0f;

  float my_score = -INFINITY;
  for (int t = 0; t < T; ++t) {
    float kd = wk_b[d];
    #pragma unroll 8
    for (int j = 0; j < D; ++j) kd = fmaf(xs[t][j], wks[j * D + d], kd);
    if (mask[b * T + t] == 0) kd = -100000.0f;
    float s = wave_reduce_sum(qd * kd) * 0.125f;
    if (d == t) my_score = s;
  }
  float m = wave_reduce_max(my_score);
  float p = (d < T) ? expf(my_score - m) : 0.f;
  float sum = wave_reduce_sum(p);
  ps[d] = p / sum;
  __syncthreads();

  float yj = 0.f;
  for (int t = 0; t < T; ++t) yj = fmaf(ps[t], xs[t][d], yj);
  ys[d] = yj;
  __syncthreads();
  float ad = wv_b[d];
  #pragma unroll 8
  for (int j = 0; j < D; ++j) ad = fmaf(ys[j], wvs[j * D + d], ad);
  atts[d] = ad;
  __syncthreads();

  float h = mlp_b[d];
  #pragma unroll 4
  for (int j = 0; j < D; ++j) h = fmaf(ug[(size_t)b * D + j], mlp_w[j * D + d], h);
  #pragma unroll 4
  for (int j = 0; j < D; ++j) h = fmaf(atts[j], mlp_w[(D + j) * D + d], h);
  h = fmaxf(h, 0.f);

  #pragma unroll
  for (int c = 0; c < 2; ++c) {
    int cc = cid[b * 2 + c];
    float s = wave_reduce_sum(h * c1[(size_t)cc * D + d]);
    if (d == 0) out[b * 2 + c] = s;
  }
}

// ---------------- host ----------------

extern "C" void kernel_launch(void* const* d_in, const int* in_sizes, int n_in,
                              void* d_out, int out_size, void* d_ws, size_t ws_size,
                              hipStream_t stream) {
  const float* usersF   = (const float*)d_in[0];
  const float* coursesF = (const float*)d_in[1];
  const float* exF      = (const float*)d_in[2];
  const float* knF      = (const float*)d_in[3];
  const float* wq_w = (const float*)d_in[4];
  const float* wq_b = (const float*)d_in[5];
  const float* wk_w = (const float*)d_in[6];
  const float* wk_b = (const float*)d_in[7];
  const float* wv_w = (const float*)d_in[8];
  const float* wv_b = (const float*)d_in[9];
  const float* mlp_w = (const float*)d_in[10];
  const float* mlp_b = (const float*)d_in[11];
  const float* pe = (const float*)d_in[12];
  const float* uc_vals = (const float*)d_in[13];
  const float* ue_vals = (const float*)d_in[14];
  const float* uk_vals = (const float*)d_in[15];
  const int* uc_src = (const int*)d_in[16];
  const int* uc_dst = (const int*)d_in[17];
  const int* ue_src = (const int*)d_in[18];
  const int* ue_dst = (const int*)d_in[19];
  const int* uk_src = (const int*)d_in[20];
  const int* uk_dst = (const int*)d_in[21];
  const int* mask = (const int*)d_in[22];
  const int* seq  = (const int*)d_in[23];
  const int* uid  = (const int*)d_in[24];
  const int* cid  = (const int*)d_in[25];

  int NU = in_sizes[0] / D;
  int NC = in_sizes[1] / D;
  int NE = in_sizes[2] / D;
  int NK = in_sizes[3] / D;
  int B  = in_sizes[24];
  int T  = in_sizes[22] / B;
  int n2_uc = in_sizes[13], n2_ue = in_sizes[14], n2_uk = in_sizes[15];

  int NImax = NC > NE ? NC : NE; NImax = NImax > NK ? NImax : NK;
  int n2max = n2_uc > n2_ue ? n2_uc : n2_ue; n2max = n2max > n2_uk ? n2max : n2_uk;
  int nchU_full = (NU + 127) >> 7;

  char* w = (char*)d_ws;
  auto alloc = [&](size_t bytes) { void* p = (void*)w; w += (bytes + 255) & ~(size_t)255; return p; };
  int2*  edata    = (int2*)alloc((size_t)n2max * 8);
  int2*  edataM   = (int2*)alloc((size_t)1048576 * 8);
  float* ul1      = (float*)alloc((size_t)NU * D * 4);
  float* il1      = (float*)alloc((size_t)NImax * D * 4);
  float* e1       = (float*)alloc((size_t)NE * D * 4);
  float* c1       = (float*)alloc((size_t)NC * D * 4);
  float* ug       = (float*)alloc((size_t)B * D * 4);
  int*   chunkptr = (int*)alloc((size_t)(NCHMAX + 1) * 4);
  int*   ccur     = (int*)alloc((size_t)NCHMAX * 4);
  int*   ghist    = (int*)alloc((size_t)8 * NCHMAX * 4);
  int*   minideg  = (int*)alloc((size_t)NU * 4);
  int*   minirp   = (int*)alloc((size_t)(NU + 1) * 4);
  int*   minicur  = (int*)alloc((size_t)NU * 4);
  int*   usel     = (int*)alloc((size_t)NU * 4);
  int*   bsum     = (int*)alloc((size_t)1024 * 4);

  hipMemsetAsync(usel, 0, (size_t)NU * 4, stream);
  mark_usel<<<(B + 255) / 256, 256, 0, stream>>>(uid, usel, B);

  auto run_graph = [&](const int* src, const int* dst, const float* vals, int n2,
                       int NI, const float* itemF, int doU, float* itemOut, int add) {
    int h = n2 / 2;
    // item chunk sizing: rows-per-chunk RI (pow2, <=64), ~>=512 chunks
    int RI = 1;
    while (RI < 64 && (RI * 2) * 512 <= NI) RI <<= 1;
    int shiftI = 0; while ((1 << shiftI) < RI) ++shiftI;
    int nchI = (NI + RI - 1) / RI;
    int nchU = doU ? nchU_full : 0;
    int nch = nchU + nchI;

    unsigned tg = (unsigned)((n2 + PA_TILE - 1) / PA_TILE);
    int nbm = (NU + SCHUNK - 1) / SCHUNK;

    hipMemsetAsync(ghist, 0, (size_t)8 * nch * 4, stream);
    hipMemsetAsync(minideg, 0, (size_t)NU * 4, stream);

    hist_both<<<tg, 256, 0, stream>>>(src, n2, h, NU, nchU, shiftI, nch, usel, minideg, ghist);
    scan_chunks<<<1, 256, 0, stream>>>(ghist, nch, chunkptr, ccur);
    scan_p1<<<(unsigned)nbm, 256, 0, stream>>>(minideg, bsum, NU);
    scan_p2<<<1, 1024, 0, stream>>>(bsum, nbm, minirp, NU);
    scan_p3<<<(unsigned)nbm, 256, 0, stream>>>(minideg, bsum, minirp, minicur, NU);
    scatter_both<<<tg, 256, 0, stream>>>(src, dst, vals, ccur, edata, n2, h, NU, nchU, shiftI, nch);
    mini_scatter<<<(unsigned)((h + 255) / 256), 256, 0, stream>>>(src, dst, vals, usel,
                                                                  minicur, edataM, h, NU);
    if (doU) {
      // full user-side layer1 (gathers itemF) -> ul1
      spmm_chunk_s<<<(unsigned)nchU, 256, 0, stream>>>(chunkptr, 0, edata, itemF, ul1, 128, NU);
      // item side fused layer1+layer2 -> il1, itemOut
      spmm_chunk_d<<<(unsigned)nchI, 256, 0, stream>>>(chunkptr, nchU, edata, usersF, ul1,
                                                       itemF, il1, itemOut, RI, NI);
    } else {
      // uk: item-side layer1 only (gathers userF) -> il1
      spmm_chunk_s<<<(unsigned)nchI, 256, 0, stream>>>(chunkptr, 0, edata, usersF, il1, RI, NI);
      // ul1 at batch rows only (gathers itemF) via mini-CSR
      spmm_l1_uid<<<(unsigned)((B + 3) / 4), 256, 0, stream>>>(minirp, edataM, itemF, ul1, uid, B);
    }
    final_uid<<<(unsigned)((B + 3) / 4), 256, 0, stream>>>(minirp, edataM, il1, ul1,
                                                           usersF, uid, ug, add, B);
  };

  run_graph(uc_src, uc_dst, uc_vals, n2_uc, NC, coursesF, 1, c1, 0);
  run_graph(ue_src, ue_dst, ue_vals, n2_ue, NE, exF,      1, e1, 1);
  run_graph(uk_src, uk_dst, uk_vals, n2_uk, NK, knF,      0, nullptr, 1);

  attn_final<<<B, 64, 0, stream>>>(e1, pe, seq, mask, wq_w, wq_b, wk_w, wk_b,
                                   wv_w, wv_b, mlp_w, mlp_b, ug, c1, cid, (float*)d_out, T);
}